// Round 6
// baseline (180.249 us; speedup 1.0000x reference)
//
#include <hip/hip_runtime.h>

typedef __attribute__((ext_vector_type(8))) short short8;
typedef __attribute__((ext_vector_type(4))) float floatx4;

#define B_   16
#define S_   4096
#define D_   128
#define P_   4096
#define CTOT 496                 // 16+32+64+128+256
#define BP   (B_ * CTOT)
#define WPADG 512                // padded wave count for decoder K
#define INV2PI 0.15915494309189535f
#define NWAVE_B 132              // encoder waves per b: 4*10+4*5+8*3+48*1
#define NJB 33                   // encoder blocks per b (132/4)

// round-to-nearest-even float -> bf16
__device__ __forceinline__ unsigned short f2bf(float f) {
    unsigned u = __float_as_uint(f);
    u += 0x7fffu + ((u >> 16) & 1u);
    return (unsigned short)(u >> 16);
}
__device__ __forceinline__ unsigned int pack2(float a, float b) {
    return (unsigned int)f2bf(a) | ((unsigned int)f2bf(b) << 16);
}

// ---------------------------------------------------------------------------
// Encoder (+ embedded wdbT pack on blockIdx.y==0 blocks).
// Grid (33, 16): per b, 132 waves; wave -> (t-tile bx, stride widx/nw over
// bx's chunk list). Waves/bx: {10,5,3,1} for chunk counts {93,45,21,9}.
// A-frags: fp32 kv direct loads + in-register bf16 convert, reused across
// chunks. B-frags: fp32 W_enc direct loads + convert (L2-resident).
// C layout (verified): col = lane&15 = c, row = quad*4+reg = t.
// EMA: final = sum_t alpha*(1-alpha)^(S-1-t)*x_t, truncated per level
// (horizons 4096/4096/1024/512/256 -> truncation error <= 1e-9).
// ---------------------------------------------------------------------------
__global__ __launch_bounds__(256) void encoder(
    const float* __restrict__ kv, const int* __restrict__ positions,
    const float* __restrict__ we0, const float* __restrict__ we1,
    const float* __restrict__ we2, const float* __restrict__ we3,
    const float* __restrict__ we4,
    const float* __restrict__ wd0, const float* __restrict__ wd1,
    const float* __restrict__ wd2, const float* __restrict__ wd3,
    const float* __restrict__ wd4,
    const float* __restrict__ bf0, const float* __restrict__ bf1,
    const float* __restrict__ bf2, const float* __restrict__ bf3,
    const float* __restrict__ bf4,
    float* __restrict__ accb,            // [3][B][CTOT], pre-zeroed
    unsigned short* __restrict__ wdbT)   // [d][w] 128x512 bf16 (decoder B)
{
    const int tid = threadIdx.x;

    // ---- embedded wdbT pack (consumed only by the NEXT dispatch) ----
    if (blockIdx.y == 0) {
        int g = blockIdx.x * 256 + tid;          // 0..8447
        int k0 = g * 8;
        if (k0 < D_ * WPADG) {                   // 65536 shorts
            int d = k0 >> 9, w0g = k0 & 511;     // 8-w group, never straddles a level
            union { unsigned int u[4]; short8 s; } r;
            if (w0g >= CTOT) {
                r.u[0] = r.u[1] = r.u[2] = r.u[3] = 0;
            } else {
                const float* src; int off, nl;
                if (w0g < 16)       { src = wd0; off = 0;   nl = 16;  }
                else if (w0g < 48)  { src = wd1; off = 16;  nl = 32;  }
                else if (w0g < 112) { src = wd2; off = 48;  nl = 64;  }
                else if (w0g < 240) { src = wd3; off = 112; nl = 128; }
                else                { src = wd4; off = 240; nl = 256; }
                const float* p = src + (size_t)d * nl + (w0g - off);
                float4 a = *(const float4*)(p);
                float4 c = *(const float4*)(p + 4);
                r.u[0] = pack2(a.x, a.y); r.u[1] = pack2(a.z, a.w);
                r.u[2] = pack2(c.x, c.y); r.u[3] = pack2(c.z, c.w);
            }
            *(short8*)(wdbT + k0) = r.s;
        }
    }

    // ---- per-wave encoder job ----
    const int b    = blockIdx.y;
    const int rem  = blockIdx.x * 4 + (tid >> 6);   // 0..131
    const int lane = tid & 63, ln15 = lane & 15, quad = lane >> 4;

    int bx, widx, nw;
    if (rem < 40)      { bx = rem / 10;               widx = rem % 10; nw = 10; }
    else if (rem < 60) { int r = rem - 40; bx = 4 + r / 5; widx = r % 5; nw = 5; }
    else if (rem < 84) { int r = rem - 60; bx = 8 + r / 3; widx = r % 3; nw = 3; }
    else               { bx = 16 + (rem - 84);        widx = 0;        nw = 1; }
    const int t0  = S_ - 64 * (bx + 1);
    const int cnt = (bx < 4) ? 93 : (bx < 8) ? 45 : (bx < 16) ? 21 : 9;

    // A-frags: fp32 direct loads, in-register bf16 convert (reused all chunks)
    const float* arow = kv + ((size_t)(b * S_ + t0 + ln15)) * D_ + quad * 8;
    short8 afr[4][4];
    #pragma unroll
    for (int m = 0; m < 4; ++m)
        #pragma unroll
        for (int k = 0; k < 4; ++k) {
            float4 x = *(const float4*)(arow + m * 16 * D_ + k * 32);
            float4 y = *(const float4*)(arow + m * 16 * D_ + k * 32 + 4);
            union { unsigned int u[4]; short8 s; } r;
            r.u[0] = pack2(x.x, x.y); r.u[1] = pack2(x.z, x.w);
            r.u[2] = pack2(y.x, y.y); r.u[3] = pack2(y.z, y.w);
            afr[m][k] = r.s;
        }

    const int   n_l[5]  = {16, 32, 64, 128, 256};
    const int   coff[5] = {0, 16, 48, 112, 240};
    const float al[5]   = {0.001f, 0.005f, 0.02f, 0.05f, 0.1f};
    const float l2m[5]  = {-0.0014434169f, -0.0072315692f, -0.0291463449f,
                           -0.0740005794f, -0.1520030934f};

    int   lprev = -1;
    float wtr[16];

    for (int ch = widx; ch < cnt; ch += nw) {
        // decode (level, chunk-within-level); cnt caps ch so constants work
        int c = ch, l = 0;
        if (c >= 3) { c -= 3; l = 1;
            if (c >= 6) { c -= 6; l = 2;
                if (c >= 12) { c -= 12; l = 3;
                    if (c >= 24) { c -= 24; l = 4; } } } }
        const int ci = c, n = n_l[l];

        if (l != lprev) {
            lprev = l;
            const float s1 = (float)(S_ - 1 - t0);
            #pragma unroll
            for (int i = 0; i < 16; ++i) {
                float trel = (float)((i >> 2) * 16 + quad * 4 + (i & 3));
                wtr[i] = al[l] * exp2f((s1 - trel) * l2m[l]);
            }
        }

        const float* wel = (l == 0) ? we0 : (l == 1) ? we1 :
                           (l == 2) ? we2 : (l == 3) ? we3 : we4;
        const float* wrow = wel + (size_t)(ci * 16 + ln15) * D_ + quad * 8;

        floatx4 acc[4];
        #pragma unroll
        for (int m = 0; m < 4; ++m) acc[m] = (floatx4){0.f, 0.f, 0.f, 0.f};
        #pragma unroll
        for (int k = 0; k < 4; ++k) {
            float4 x = *(const float4*)(wrow + k * 32);
            float4 y = *(const float4*)(wrow + k * 32 + 4);
            union { unsigned int u[4]; short8 s; } r;
            r.u[0] = pack2(x.x, x.y); r.u[1] = pack2(x.z, x.w);
            r.u[2] = pack2(y.x, y.y); r.u[3] = pack2(y.z, y.w);
            #pragma unroll
            for (int m = 0; m < 4; ++m)
                acc[m] = __builtin_amdgcn_mfma_f32_16x16x32_bf16(
                             afr[m][k], r.s, acc[m], 0, 0, 0);
        }

        const int kind  = (ci * 16) / n;          // chunk lies in one kind
        const int local = ci * 16 + ln15 - kind * n;
        float s = 0.0f;
        if (kind == 0) {
            const float* bfl = (l == 0) ? bf0 : (l == 1) ? bf1 :
                               (l == 2) ? bf2 : (l == 3) ? bf3 : bf4;
            const float bsv = bfl[local];
            #pragma unroll
            for (int m = 0; m < 4; ++m) {
                int4 pi = *(const int4*)(positions + t0 + m * 16 + quad * 4);
                float pfv[4] = {(float)pi.x, (float)pi.y, (float)pi.z, (float)pi.w};
                #pragma unroll
                for (int r = 0; r < 4; ++r) {
                    float rev = bsv * pfv[r] * (1.0f / 8192.0f);
                    rev -= floorf(rev);
                    s += wtr[m * 4 + r] * acc[m][r] * __builtin_amdgcn_sinf(rev);
                }
            }
        } else if (kind == 1) {
            #pragma unroll
            for (int m = 0; m < 4; ++m)
                #pragma unroll
                for (int r = 0; r < 4; ++r)
                    s += wtr[m * 4 + r] * fabsf(acc[m][r]);
        } else {
            #pragma unroll
            for (int m = 0; m < 4; ++m)
                #pragma unroll
                for (int r = 0; r < 4; ++r)
                    s += wtr[m * 4 + r] * acc[m][r];
        }
        s += __shfl_xor(s, 16);
        s += __shfl_xor(s, 32);
        if (lane < 16)
            atomicAdd(accb + (size_t)kind * BP + b * CTOT + coff[l] + local, s);
    }
}

// ---------------------------------------------------------------------------
// Decoder (combine folded): per block compute Q/A/P params from accb in regs,
// then out[b,p,:] = sum_w A*sin(2pi*rev) * wd[w,:] via bf16 MFMA.
// Block 64p x 128d; K=512 in 2 passes of 256 -> v[64][264] bf16 (34 KB LDS,
// 4 blocks/CU). C layout: col = lane&15 -> d, row = quad*4+reg -> p.
// ---------------------------------------------------------------------------
__global__ __launch_bounds__(256) void decoder(
    const float* __restrict__ accb,
    const float* __restrict__ b0, const float* __restrict__ b1,
    const float* __restrict__ b2, const float* __restrict__ b3,
    const float* __restrict__ b4,
    const unsigned short* __restrict__ wdbT, const int* __restrict__ rpos,
    float* __restrict__ out)
{
    __shared__ unsigned short v[64 * 264];
    __shared__ float rpn[64];
    const int b = blockIdx.y, p0 = blockIdx.x * 64, tid = threadIdx.x;
    if (tid < 64) rpn[tid] = (float)rpos[p0 + tid] * (1.0f / 8192.0f);

    // combine: this thread's column params for both halves (w = h*256 + tid)
    float Qv[2], Av[2], Pv[2];
    #pragma unroll
    for (int h = 0; h < 2; ++h) {
        int w = h * 256 + tid;
        float A = 0.f, Q = 0.f, P = 0.f;
        if (w < CTOT) {
            const float* bfl; int off;
            if (w < 16)       { bfl = b0; off = 0;   }
            else if (w < 48)  { bfl = b1; off = 16;  }
            else if (w < 112) { bfl = b2; off = 48;  }
            else if (w < 240) { bfl = b3; off = 112; }
            else              { bfl = b4; off = 240; }
            float f  = accb[0 * BP + b * CTOT + w];
            A        = accb[1 * BP + b * CTOT + w];
            float ph = accb[2 * BP + b * CTOT + w];
            Q = f + bfl[w - off];
            P = ph * INV2PI;
        }
        Qv[h] = Q; Av[h] = A; Pv[h] = P;
    }

    const int wid = tid >> 6, lane = tid & 63, ln = lane & 15, quad = lane >> 4;
    const int nt0 = wid * 2;

    floatx4 acc[4][2];
    #pragma unroll
    for (int m = 0; m < 4; ++m)
        #pragma unroll
        for (int j = 0; j < 2; ++j) acc[m][j] = (floatx4){0.f, 0.f, 0.f, 0.f};

    #pragma unroll
    for (int half = 0; half < 2; ++half) {
        const int w0 = half * 256;
        const float Q = Qv[half], A = Av[half], Ph = Pv[half];
        __syncthreads();   // prior MFMA reads done (and rpn ready on pass 0)
        for (int p = 0; p < 64; ++p) {
            float r = fmaf(Q, rpn[p], Ph);
            r -= floorf(r);
            v[p * 264 + tid] = f2bf(A * __builtin_amdgcn_sinf(r));
        }
        __syncthreads();

        #pragma unroll
        for (int kk = 0; kk < 8; ++kk) {
            short8 bn[2];
            #pragma unroll
            for (int j = 0; j < 2; ++j)
                bn[j] = *(const short8*)(wdbT + (size_t)((nt0 + j) * 16 + ln) * WPADG
                                         + w0 + kk * 32 + quad * 8);
            short8 am[4];
            #pragma unroll
            for (int m = 0; m < 4; ++m)
                am[m] = *(const short8*)&v[(m * 16 + ln) * 264 + kk * 32 + quad * 8];
            #pragma unroll
            for (int m = 0; m < 4; ++m)
                #pragma unroll
                for (int j = 0; j < 2; ++j)
                    acc[m][j] = __builtin_amdgcn_mfma_f32_16x16x32_bf16(
                                    am[m], bn[j], acc[m][j], 0, 0, 0);
        }
    }

    #pragma unroll
    for (int m = 0; m < 4; ++m)
        #pragma unroll
        for (int j = 0; j < 2; ++j)
            #pragma unroll
            for (int r = 0; r < 4; ++r) {
                int p = p0 + m * 16 + quad * 4 + r;
                int d = (nt0 + j) * 16 + ln;
                out[((size_t)(b * P_ + p)) * D_ + d] = acc[m][j][r];
            }
}

// ---------------------------------------------------------------------------
extern "C" void kernel_launch(void* const* d_in, const int* in_sizes, int n_in,
                              void* d_out, int out_size, void* d_ws, size_t ws_size,
                              hipStream_t stream)
{
    const float* kv        = (const float*)d_in[0];
    const int*   positions = (const int*)d_in[1];
    const int*   rpos      = (const int*)d_in[2];

    char* ws = (char*)d_ws;
    float*          accb = (float*)(ws + 0);               // 95232 B
    unsigned short* wdbT = (unsigned short*)(ws + 95232);  // 131072 B

    hipMemsetAsync(accb, 0, (size_t)(3 * BP) * sizeof(float), stream);

    encoder<<<dim3(NJB, B_), 256, 0, stream>>>(
        kv, positions,
        (const float*)d_in[3], (const float*)d_in[6], (const float*)d_in[9],
        (const float*)d_in[12], (const float*)d_in[15],
        (const float*)d_in[4], (const float*)d_in[7], (const float*)d_in[10],
        (const float*)d_in[13], (const float*)d_in[16],
        (const float*)d_in[5], (const float*)d_in[8], (const float*)d_in[11],
        (const float*)d_in[14], (const float*)d_in[17],
        accb, wdbT);

    decoder<<<dim3(P_ / 64, B_), 256, 0, stream>>>(
        accb,
        (const float*)d_in[5], (const float*)d_in[8], (const float*)d_in[11],
        (const float*)d_in[14], (const float*)d_in[17],
        wdbT, rpos, (float*)d_out);
}

// Round 7
// 166.028 us; speedup vs baseline: 1.0857x; 1.0857x over previous
//
#include <hip/hip_runtime.h>

typedef __attribute__((ext_vector_type(8))) short short8;
typedef __attribute__((ext_vector_type(4))) float floatx4;

#define B_   16
#define S_   4096
#define D_   128
#define P_   4096
#define CTOT 496                 // 16+32+64+128+256
#define BP   (B_ * CTOT)
#define WPADG 512                // padded wave count for decoder K
#define INV2PI 0.15915494309189535f
#define NJB 336                  // encoder blocks per b (balanced)

// round-to-nearest-even float -> bf16
__device__ __forceinline__ unsigned short f2bf(float f) {
    unsigned u = __float_as_uint(f);
    u += 0x7fffu + ((u >> 16) & 1u);
    return (unsigned short)(u >> 16);
}
__device__ __forceinline__ unsigned int pack2(float a, float b) {
    return (unsigned int)f2bf(a) | ((unsigned int)f2bf(b) << 16);
}

// ---------------------------------------------------------------------------
// Encoder, R3-proven shape: grid (336, 16); block stages one 64t x 128d kv
// tile to LDS (bf16), then each of the 4 waves computes ONE 16-column chunk:
// 16 MFMAs + EMA epilogue + 16 atomics. Balanced block counts per t-tile:
// {24,12,6,3} blocks for chunk counts {93,45,21,9} (t-tiles from the end;
// EMA horizons 4096/4096/1024/512/256 -> truncation error <= 1e-9).
// B-frags read direct from fp32 W_enc (L2-hot) + in-register bf16 pack.
// C layout (verified): col = lane&15 = c, row = quad*4+reg = t.
// wdbT pack for the decoder is embedded in (b==0, bid<32) blocks.
// ---------------------------------------------------------------------------
__global__ __launch_bounds__(256) void encoder(
    const float* __restrict__ kv, const int* __restrict__ positions,
    const float* __restrict__ we0, const float* __restrict__ we1,
    const float* __restrict__ we2, const float* __restrict__ we3,
    const float* __restrict__ we4,
    const float* __restrict__ wd0, const float* __restrict__ wd1,
    const float* __restrict__ wd2, const float* __restrict__ wd3,
    const float* __restrict__ wd4,
    const float* __restrict__ bf0, const float* __restrict__ bf1,
    const float* __restrict__ bf2, const float* __restrict__ bf3,
    const float* __restrict__ bf4,
    float* __restrict__ accb,            // [3][B][CTOT], pre-zeroed
    unsigned short* __restrict__ wdbT)   // [d][w] 128x512 bf16 (decoder B)
{
    __shared__ unsigned short kvb[64 * 136];   // [t][d] bf16, stride 136 (2-way free)
    __shared__ float pf[64];
    const int tid = threadIdx.x;
    const int b   = blockIdx.y;
    const int bid = blockIdx.x;

    // ---- embedded wdbT pack (consumed only by the NEXT dispatch) ----
    if (b == 0 && bid < 32) {
        int k0 = (bid * 256 + tid) * 8;          // < 65536
        int d = k0 >> 9, w0g = k0 & 511;         // 8-w group, never straddles a level
        union { unsigned int u[4]; short8 s; } r;
        if (w0g >= CTOT) {
            r.u[0] = r.u[1] = r.u[2] = r.u[3] = 0;
        } else {
            const float* src; int off, nl;
            if (w0g < 16)       { src = wd0; off = 0;   nl = 16;  }
            else if (w0g < 48)  { src = wd1; off = 16;  nl = 32;  }
            else if (w0g < 112) { src = wd2; off = 48;  nl = 64;  }
            else if (w0g < 240) { src = wd3; off = 112; nl = 128; }
            else                { src = wd4; off = 240; nl = 256; }
            const float* p = src + (size_t)d * nl + (w0g - off);
            float4 a = *(const float4*)(p);
            float4 c = *(const float4*)(p + 4);
            r.u[0] = pack2(a.x, a.y); r.u[1] = pack2(a.z, a.w);
            r.u[2] = pack2(c.x, c.y); r.u[3] = pack2(c.z, c.w);
        }
        *(short8*)(wdbT + k0) = r.s;
    }

    // ---- decode (t-tile bx, local block lb) from balanced prefix ----
    int bx, lb;
    if (bid < 96)       { bx = bid / 24;            lb = bid % 24; }
    else if (bid < 144) { int r = bid - 96;  bx = 4 + r / 12; lb = r % 12; }
    else if (bid < 192) { int r = bid - 144; bx = 8 + r / 6;  lb = r % 6;  }
    else                { int r = bid - 192; bx = 16 + r / 3; lb = r % 3;  }
    const int t0  = S_ - 64 * (bx + 1);
    const int cnt = (bx < 4) ? 93 : (bx < 8) ? 45 : (bx < 16) ? 21 : 9;

    // ---- stage kv tile: fp32 float4 -> bf16 LDS ----
    const float* src = kv + ((size_t)(b * S_ + t0)) * D_;
    #pragma unroll
    for (int f = 0; f < 8; ++f) {
        int idx = f * 256 + tid;
        int t = idx >> 5, d4 = idx & 31;
        float4 val = *(const float4*)(src + t * D_ + d4 * 4);
        unsigned long long u = (unsigned long long)pack2(val.x, val.y)
                             | ((unsigned long long)pack2(val.z, val.w) << 32);
        *(unsigned long long*)&kvb[t * 136 + d4 * 4] = u;
    }
    if (tid < 64) pf[tid] = (float)positions[t0 + tid] * (1.0f / 8192.0f);
    __syncthreads();

    const int wid = tid >> 6, lane = tid & 63, ln15 = lane & 15, quad = lane >> 4;
    const int jid = lb * 4 + wid;
    if (jid >= cnt) return;                       // no barriers past this point

    // ---- decode (level, chunk-within-level) ----
    int c = jid, l = 0;
    if (c >= 3) { c -= 3; l = 1;
        if (c >= 6) { c -= 6; l = 2;
            if (c >= 12) { c -= 12; l = 3;
                if (c >= 24) { c -= 24; l = 4; } } } }
    const int ci = c;
    const int   n_l[5]  = {16, 32, 64, 128, 256};
    const int   coff[5] = {0, 16, 48, 112, 240};
    const float al[5]   = {0.001f, 0.005f, 0.02f, 0.05f, 0.1f};
    const float l2m[5]  = {-0.0014434169f, -0.0072315692f, -0.0291463449f,
                           -0.0740005794f, -0.1520030934f};
    const int n = n_l[l];

    // EMA weights for this lane's 16 (m,r) rows
    float wtr[16];
    {
        const float s1 = (float)(S_ - 1 - t0);
        #pragma unroll
        for (int i = 0; i < 16; ++i) {
            float trel = (float)((i >> 2) * 16 + quad * 4 + (i & 3));
            wtr[i] = al[l] * exp2f((s1 - trel) * l2m[l]);
        }
    }

    // ---- GEMM: A from LDS, B direct fp32 + pack ----
    const float* wel = (l == 0) ? we0 : (l == 1) ? we1 :
                       (l == 2) ? we2 : (l == 3) ? we3 : we4;
    const float* wrow = wel + (size_t)(ci * 16 + ln15) * D_ + quad * 8;

    floatx4 acc[4];
    #pragma unroll
    for (int m = 0; m < 4; ++m) acc[m] = (floatx4){0.f, 0.f, 0.f, 0.f};
    #pragma unroll
    for (int k = 0; k < 4; ++k) {
        float4 x = *(const float4*)(wrow + k * 32);
        float4 y = *(const float4*)(wrow + k * 32 + 4);
        union { unsigned int u[4]; short8 s; } r;
        r.u[0] = pack2(x.x, x.y); r.u[1] = pack2(x.z, x.w);
        r.u[2] = pack2(y.x, y.y); r.u[3] = pack2(y.z, y.w);
        #pragma unroll
        for (int m = 0; m < 4; ++m) {
            short8 af = *(const short8*)&kvb[(m * 16 + ln15) * 136 + k * 32 + quad * 8];
            acc[m] = __builtin_amdgcn_mfma_f32_16x16x32_bf16(af, r.s, acc[m], 0, 0, 0);
        }
    }

    // ---- epilogue: EMA weight + kind transform, quad-reduce, atomics ----
    const int kind  = (ci * 16) / n;              // chunk lies in one kind
    const int local = ci * 16 + ln15 - kind * n;
    float s = 0.0f;
    if (kind == 0) {
        const float* bfl = (l == 0) ? bf0 : (l == 1) ? bf1 :
                           (l == 2) ? bf2 : (l == 3) ? bf3 : bf4;
        const float bsv = bfl[local];
        #pragma unroll
        for (int m = 0; m < 4; ++m)
            #pragma unroll
            for (int r = 0; r < 4; ++r) {
                float rev = bsv * pf[m * 16 + quad * 4 + r];  // sin(2pi*base*pos/8192)
                rev -= floorf(rev);
                s += wtr[m * 4 + r] * acc[m][r] * __builtin_amdgcn_sinf(rev);
            }
    } else if (kind == 1) {
        #pragma unroll
        for (int m = 0; m < 4; ++m)
            #pragma unroll
            for (int r = 0; r < 4; ++r)
                s += wtr[m * 4 + r] * fabsf(acc[m][r]);
    } else {
        #pragma unroll
        for (int m = 0; m < 4; ++m)
            #pragma unroll
            for (int r = 0; r < 4; ++r)
                s += wtr[m * 4 + r] * acc[m][r];
    }
    s += __shfl_xor(s, 16);
    s += __shfl_xor(s, 32);
    if (lane < 16)
        atomicAdd(accb + (size_t)kind * BP + b * CTOT + coff[l] + local, s);
}

// ---------------------------------------------------------------------------
// Decoder (combine folded): per block compute Q/A/P params from accb in regs,
// then out[b,p,:] = sum_w A*sin(2pi*rev) * wd[w,:] via bf16 MFMA.
// Block 64p x 128d; K=512 in 2 passes of 256 -> v[64][264] bf16 (34 KB LDS,
// 4 blocks/CU). C layout: col = lane&15 -> d, row = quad*4+reg -> p.
// ---------------------------------------------------------------------------
__global__ __launch_bounds__(256) void decoder(
    const float* __restrict__ accb,
    const float* __restrict__ b0, const float* __restrict__ b1,
    const float* __restrict__ b2, const float* __restrict__ b3,
    const float* __restrict__ b4,
    const unsigned short* __restrict__ wdbT, const int* __restrict__ rpos,
    float* __restrict__ out)
{
    __shared__ unsigned short v[64 * 264];
    __shared__ float rpn[64];
    const int b = blockIdx.y, p0 = blockIdx.x * 64, tid = threadIdx.x;
    if (tid < 64) rpn[tid] = (float)rpos[p0 + tid] * (1.0f / 8192.0f);

    // combine: this thread's column params for both halves (w = h*256 + tid)
    float Qv[2], Av[2], Pv[2];
    #pragma unroll
    for (int h = 0; h < 2; ++h) {
        int w = h * 256 + tid;
        float A = 0.f, Q = 0.f, P = 0.f;
        if (w < CTOT) {
            const float* bfl; int off;
            if (w < 16)       { bfl = b0; off = 0;   }
            else if (w < 48)  { bfl = b1; off = 16;  }
            else if (w < 112) { bfl = b2; off = 48;  }
            else if (w < 240) { bfl = b3; off = 112; }
            else              { bfl = b4; off = 240; }
            float f  = accb[0 * BP + b * CTOT + w];
            A        = accb[1 * BP + b * CTOT + w];
            float ph = accb[2 * BP + b * CTOT + w];
            Q = f + bfl[w - off];
            P = ph * INV2PI;
        }
        Qv[h] = Q; Av[h] = A; Pv[h] = P;
    }

    const int wid = tid >> 6, lane = tid & 63, ln = lane & 15, quad = lane >> 4;
    const int nt0 = wid * 2;

    floatx4 acc[4][2];
    #pragma unroll
    for (int m = 0; m < 4; ++m)
        #pragma unroll
        for (int j = 0; j < 2; ++j) acc[m][j] = (floatx4){0.f, 0.f, 0.f, 0.f};

    #pragma unroll
    for (int half = 0; half < 2; ++half) {
        const int w0 = half * 256;
        const float Q = Qv[half], A = Av[half], Ph = Pv[half];
        __syncthreads();   // prior MFMA reads done (and rpn ready on pass 0)
        for (int p = 0; p < 64; ++p) {
            float r = fmaf(Q, rpn[p], Ph);
            r -= floorf(r);
            v[p * 264 + tid] = f2bf(A * __builtin_amdgcn_sinf(r));
        }
        __syncthreads();

        #pragma unroll
        for (int kk = 0; kk < 8; ++kk) {
            short8 bn[2];
            #pragma unroll
            for (int j = 0; j < 2; ++j)
                bn[j] = *(const short8*)(wdbT + (size_t)((nt0 + j) * 16 + ln) * WPADG
                                         + w0 + kk * 32 + quad * 8);
            short8 am[4];
            #pragma unroll
            for (int m = 0; m < 4; ++m)
                am[m] = *(const short8*)&v[(m * 16 + ln) * 264 + kk * 32 + quad * 8];
            #pragma unroll
            for (int m = 0; m < 4; ++m)
                #pragma unroll
                for (int j = 0; j < 2; ++j)
                    acc[m][j] = __builtin_amdgcn_mfma_f32_16x16x32_bf16(
                                    am[m], bn[j], acc[m][j], 0, 0, 0);
        }
    }

    #pragma unroll
    for (int m = 0; m < 4; ++m)
        #pragma unroll
        for (int j = 0; j < 2; ++j)
            #pragma unroll
            for (int r = 0; r < 4; ++r) {
                int p = p0 + m * 16 + quad * 4 + r;
                int d = (nt0 + j) * 16 + ln;
                out[((size_t)(b * P_ + p)) * D_ + d] = acc[m][j][r];
            }
}

// ---------------------------------------------------------------------------
extern "C" void kernel_launch(void* const* d_in, const int* in_sizes, int n_in,
                              void* d_out, int out_size, void* d_ws, size_t ws_size,
                              hipStream_t stream)
{
    const float* kv        = (const float*)d_in[0];
    const int*   positions = (const int*)d_in[1];
    const int*   rpos      = (const int*)d_in[2];

    char* ws = (char*)d_ws;
    float*          accb = (float*)(ws + 0);               // 95232 B
    unsigned short* wdbT = (unsigned short*)(ws + 95232);  // 131072 B

    hipMemsetAsync(accb, 0, (size_t)(3 * BP) * sizeof(float), stream);

    encoder<<<dim3(NJB, B_), 256, 0, stream>>>(
        kv, positions,
        (const float*)d_in[3], (const float*)d_in[6], (const float*)d_in[9],
        (const float*)d_in[12], (const float*)d_in[15],
        (const float*)d_in[4], (const float*)d_in[7], (const float*)d_in[10],
        (const float*)d_in[13], (const float*)d_in[16],
        (const float*)d_in[5], (const float*)d_in[8], (const float*)d_in[11],
        (const float*)d_in[14], (const float*)d_in[17],
        accb, wdbT);

    decoder<<<dim3(P_ / 64, B_), 256, 0, stream>>>(
        accb,
        (const float*)d_in[5], (const float*)d_in[8], (const float*)d_in[11],
        (const float*)d_in[14], (const float*)d_in[17],
        wdbT, rpos, (float*)d_out);
}